// Round 11
// baseline (169.119 us; speedup 1.0000x reference)
//
#include <hip/hip_runtime.h>
#include <hip/hip_bf16.h>

#define B_ 2
#define L_ 2048
#define H_ 8
#define DK_ 64
#define DQ_ 256
#define DM_ 512
#define NKW 64                        // L_/32 mask words per row
#define QSCALE 0.18033688011112042f   // log2(e) / sqrt(D_K)

typedef short short4v __attribute__((ext_vector_type(4)));
typedef short short8v __attribute__((ext_vector_type(8)));
typedef float f32x16 __attribute__((ext_vector_type(16)));
typedef float f32x4v __attribute__((ext_vector_type(4)));
typedef unsigned long long u64x4 __attribute__((ext_vector_type(4)));

// RNE f32 -> bf16 (matches hardware/numpy; inputs here are never NaN/Inf)
__device__ __forceinline__ short f2bf(float f){
  unsigned u = __float_as_uint(f);
  unsigned r = (u + 0x7FFFu + ((u >> 16) & 1u)) >> 16;
  return (short)r;
}
__device__ __forceinline__ float bf2f(short s){
  return __uint_as_float(((unsigned)(unsigned short)s) << 16);
}

__device__ __forceinline__ f32x16 mfma_b(short4v a, short4v b, f32x16 c){
  // v_mfma_f32_32x32x8_bf16 (1k): A[i][k]: i=l%32, k=4*(l/32)+b
  // B[k][j]: j=l%32, k=4*(l/32)+b ; D[i][j]: j=l%32, i=(reg&3)+8*(reg>>2)+4*(l>>5)
  return __builtin_amdgcn_mfma_f32_32x32x8bf16_1k(a, b, c, 0, 0, 0);
}

// ---------------- 1. weights -> fragment-major bf16 ----------------
__global__ void k_wprep(const float* __restrict__ Wq, const float* __restrict__ Wk,
                        const float* __restrict__ Wv, const float* __restrict__ Wfc,
                        short* __restrict__ wqf, short* __restrict__ wkf,
                        short* __restrict__ wvf, short* __restrict__ wfcf){
  int which = blockIdx.y;
  const float* src; short* dst; int K, N;
  if (which == 0){ src = Wq;  dst = wqf;  K = DQ_; N = DM_; }
  else if (which == 1){ src = Wk;  dst = wkf;  K = DM_; N = DM_; }
  else if (which == 2){ src = Wv;  dst = wvf;  K = DM_; N = DM_; }
  else { src = Wfc; dst = wfcf; K = DM_; N = DM_; }
  int K4 = K >> 2;
  long long e0 = ((long long)blockIdx.x * 256 + threadIdx.x) * 8;
  if (e0 >= (long long)K * N) return;
  short8v o;
  #pragma unroll
  for (int u = 0; u < 8; u++){
    long long e = e0 + u;
    int km = (int)(e & 3), j = (int)((e >> 2) & 31);
    int rest = (int)(e >> 7);
    int k4 = rest % K4, nt = rest / K4;
    o[u] = f2bf(src[(long long)(k4*4 + km)*N + nt*32 + j]);
  }
  *(short8v*)(dst + e0) = o;
}

// ---------------- 2. QKV projection GEMM (y<3) + mask bit-pack (y==3) ----------------
__launch_bounds__(256, 4)
__global__ void k_projmask(const float* __restrict__ qs, const float* __restrict__ ks, const float* __restrict__ vs,
                           const short* __restrict__ wqf, const short* __restrict__ wkf, const short* __restrict__ wvf,
                           short* __restrict__ qh, short* __restrict__ kfr, short* __restrict__ vf,
                           const int* __restrict__ mask, unsigned long long* __restrict__ bits){
  int which = blockIdx.y;
  if (which == 3){
    const long long nwords = (long long)B_ * L_ * L_ / 64;
    int l = threadIdx.x & 63;
    long long wid = ((long long)blockIdx.x * 256 + threadIdx.x) >> 6;
    long long nw  = ((long long)gridDim.x * 256) >> 6;
    for (long long w0 = wid * 4; w0 < nwords; w0 += nw * 4){
      const int* p = mask + w0 * 64 + l;
      unsigned long long b0 = __ballot(p[0]   != 0);
      unsigned long long b1 = __ballot(p[64]  != 0);
      unsigned long long b2 = __ballot(p[128] != 0);
      unsigned long long b3 = __ballot(p[192] != 0);
      if (l == 0){
        u64x4 o; o.x = b0; o.y = b1; o.z = b2; o.w = b3;
        *(u64x4*)(bits + w0) = o;
      }
    }
    return;
  }
  const float* src; const short* wt; int K; float scale;
  if (which == 0){ src = qs; wt = wqf; K = DQ_; scale = QSCALE; }
  else if (which == 1){ src = ks; wt = wkf; K = DM_; scale = 1.f; }
  else { src = vs; wt = wvf; K = DM_; scale = 1.f; }
  int K4 = K >> 2;

  int t = threadIdx.x, w = t >> 6, l = t & 63, l31 = l & 31, hh = l >> 5;
  int m0 = blockIdx.x * 32;
  const float* arow = src + (long long)(m0 + l31) * K + 4*hh;

  f32x16 acc[4] = {};
  for (int k0 = 0; k0 < K; k0 += 32){
    short4v af[4];
    #pragma unroll
    for (int c = 0; c < 4; c++){
      float4 a4 = *(const float4*)(arow + k0 + 8*c);
      af[c].x = f2bf(a4.x); af[c].y = f2bf(a4.y); af[c].z = f2bf(a4.z); af[c].w = f2bf(a4.w);
    }
    #pragma unroll
    for (int c = 0; c < 4; c++){
      #pragma unroll
      for (int nt = 0; nt < 4; nt++){
        int ntg = w*4 + nt;
        const short* bp = wt + ((long long)(ntg*K4 + (k0>>2) + 2*c + hh)*32 + l31)*4;
        acc[nt] = mfma_b(af[c], *(const short4v*)bp, acc[nt]);
      }
    }
  }

  if (which == 0){
    #pragma unroll
    for (int nt = 0; nt < 4; nt++){
      int n = (w*4 + nt)*32 + l31;
      int h_ = n >> 6, dk = n & 63;
      #pragma unroll
      for (int r = 0; r < 16; r++){
        int m = m0 + (r&3) + 8*(r>>2) + 4*hh;
        int b = m >> 11, lq = m & 2047;
        qh[((long long)(b*H_ + h_)*L_ + lq)*DK_ + dk] = f2bf(acc[nt][r] * scale);
      }
    }
  } else if (which == 1){
    #pragma unroll
    for (int nt = 0; nt < 4; nt++){
      int n = (w*4 + nt)*32 + l31;
      int h_ = n >> 6, dk = n & 63;
      #pragma unroll
      for (int r = 0; r < 16; r++){
        int m = m0 + (r&3) + 8*(r>>2) + 4*hh;
        int b = m >> 11, lq = m & 2047;
        long long idx = ((((long long)(b*H_ + h_)*64 + (lq>>5))*16 + (dk>>2))*32 + (lq&31))*4 + (dk&3);
        kfr[idx] = f2bf(acc[nt][r]);
      }
    }
  } else {
    #pragma unroll
    for (int nt = 0; nt < 4; nt++){
      int n = (w*4 + nt)*32 + l31;
      int h_ = n >> 6, dv = n & 63;
      #pragma unroll
      for (int rg = 0; rg < 4; rg++){
        int m = m0 + 8*rg + 4*hh;
        int b = m >> 11, lq = m & 2047;
        short4v o;
        o.x = f2bf(acc[nt][4*rg+0]); o.y = f2bf(acc[nt][4*rg+1]);
        o.z = f2bf(acc[nt][4*rg+2]); o.w = f2bf(acc[nt][4*rg+3]);
        long long idx = (((long long)(b*H_ + h_)*512 + (lq>>2))*64 + dv)*4;
        *(short4v*)(vf + idx) = o;
      }
    }
  }
}

// ---------------- 3. merged attention with double-buffered K-fragment prefetch ----------------
__launch_bounds__(256, 4)
__global__ void k_attn(const short* __restrict__ qh, const short* __restrict__ kfr,
                       const short* __restrict__ vf, const unsigned* __restrict__ bits,
                       short* __restrict__ attf, float* __restrict__ attn){
  __shared__ unsigned bitsl[32][65];
  __shared__ float rs[4][32];
  __shared__ float inv_l[32];
  __shared__ float shbuf[4608];        // pvb: (w*32+qr)*36+i ; tile: row*132+col

  int wg = blockIdx.x;
  wg = (wg & 7) * 128 + (wg >> 3);     // XCD-chunked swizzle (1024 % 8 == 0)
  int qt = wg & 63, bh = wg >> 6;
  int b = bh >> 3, h_ = bh & 7;
  int q0 = qt * 32;
  int t = threadIdx.x, w = t >> 6, l = t & 63, l31 = l & 31, hh = l >> 5;

  for (int i = t; i < 32 * 64; i += 256){
    int qq = i >> 6, wd = i & 63;
    bitsl[qq][wd] = bits[(long long)(b*L_ + q0 + qq)*NKW + wd];
  }

  const short* qbase = qh  + ((long long)bh*L_ + q0 + l31) * DK_;
  const short* kbase = kfr + (long long)bh * L_ * DK_;
  const short* vbase = vf  + (long long)bh * L_ * DK_;

  short4v qf[8];
  #pragma unroll
  for (int c = 0; c < 8; c++) qf[c] = *(const short4v*)(qbase + 8*c + 4*hh);

  __syncthreads();

  // ---- pass 1: S^T = mfma(K,Q); double-buffered kf prefetch
  f32x16 pv0 = {}, pv1 = {};
  float rowsum = 0.f;
  short4v kfA[8], kfB[8];

#define LOADKF(dst, kidx) { \
    const short* kp_ = kbase + (long long)((kidx) >> 5) * 2048 + l31*4; \
    _Pragma("unroll") \
    for (int c = 0; c < 8; c++) dst[c] = *(const short4v*)(kp_ + (2*c + hh)*128); }

#define P1BODY(tt, kf) { \
    int k0 = w*512 + (tt)*32; \
    f32x16 s = {}; \
    _Pragma("unroll") \
    for (int c = 0; c < 8; c++) s = mfma_b(kf[c], qf[c], s); \
    unsigned mw = bitsl[l31][k0 >> 5]; \
    _Pragma("unroll") \
    for (int j = 0; j < 4; j++){ \
      short4v a; \
      _Pragma("unroll") \
      for (int i = 0; i < 4; i++){ \
        float ev = __builtin_amdgcn_exp2f(s[4*j + i]); \
        ev = ((mw >> (i + 8*j + 4*hh)) & 1u) ? ev : 0.f; \
        rowsum += ev; \
        a[i] = f2bf(ev); \
      } \
      const short* vp = vbase + (long long)((k0>>2) + 2*j + hh) * 256; \
      short4v v0 = *(const short4v*)(vp + l31*4); \
      short4v v1 = *(const short4v*)(vp + (32 + l31)*4); \
      pv0 = mfma_b(a, v0, pv0); \
      pv1 = mfma_b(a, v1, pv1); \
    } }

  LOADKF(kfA, w*512)
  #pragma unroll 1
  for (int tt = 0; tt < 16; tt += 2){
    LOADKF(kfB, w*512 + (tt+1)*32)
    P1BODY(tt, kfA)
    if (tt + 2 < 16) LOADKF(kfA, w*512 + (tt+2)*32)
    P1BODY(tt+1, kfB)
  }

  rowsum += __shfl_xor(rowsum, 32, 64);
  if (l < 32) rs[w][l] = rowsum;
  __syncthreads();

  long long mtbase = (long long)((b*L_ + q0) >> 5) * 16384;

  // round A: reduce pv0 (dv 0..31)
  #pragma unroll
  for (int r = 0; r < 16; r++){
    int qr = (r&3) + 8*(r>>2) + 4*hh;
    shbuf[(w*32 + qr)*36 + l31] = pv0[r];
  }
  if (t < 32) inv_l[t] = 1.f / (rs[0][t] + rs[1][t] + rs[2][t] + rs[3][t]);
  __syncthreads();
  {
    int qq = t >> 3, dv0 = (t & 7) * 4;
    float iq = inv_l[qq];
    float a0=0,a1=0,a2=0,a3=0;
    #pragma unroll
    for (int ww = 0; ww < 4; ww++){
      const float* pb = &shbuf[(ww*32 + qq)*36 + dv0];
      a0 += pb[0]; a1 += pb[1]; a2 += pb[2]; a3 += pb[3];
    }
    short4v o; o.x = f2bf(a0*iq); o.y = f2bf(a1*iq); o.z = f2bf(a2*iq); o.w = f2bf(a3*iq);
    *(short4v*)(attf + mtbase + ((long long)(h_*16 + (t&7))*32 + qq)*4) = o;
  }
  __syncthreads();

  // round B: reduce pv1 (dv 32..63)
  #pragma unroll
  for (int r = 0; r < 16; r++){
    int qr = (r&3) + 8*(r>>2) + 4*hh;
    shbuf[(w*32 + qr)*36 + l31] = pv1[r];
  }
  __syncthreads();
  {
    int qq = t >> 3, dv0 = (t & 7) * 4;
    float iq = inv_l[qq];
    float a0=0,a1=0,a2=0,a3=0;
    #pragma unroll
    for (int ww = 0; ww < 4; ww++){
      const float* pb = &shbuf[(ww*32 + qq)*36 + dv0];
      a0 += pb[0]; a1 += pb[1]; a2 += pb[2]; a3 += pb[3];
    }
    short4v o; o.x = f2bf(a0*iq); o.y = f2bf(a1*iq); o.z = f2bf(a2*iq); o.w = f2bf(a3*iq);
    *(short4v*)(attf + mtbase + ((long long)(h_*16 + 8 + (t&7))*32 + qq)*4) = o;
  }
  __syncthreads();                     // pvb readers done before shbuf becomes tile

  // ---- pass 2: S = mfma(Q,K), C-init = log2(inv); kf prefetched across store barriers
  f32x16 linv;
  #pragma unroll
  for (int r = 0; r < 16; r++) linv[r] = __log2f(inv_l[(r&3) + 8*(r>>2) + 4*hh]);

  float* abase = attn + ((long long)bh*L_ + q0) * L_;
  int srow = t >> 5, scol = (t & 31) * 4;

#define P2BODY(round, kf) { \
    f32x16 s = linv; \
    _Pragma("unroll") \
    for (int c = 0; c < 8; c++) s = mfma_b(qf[c], kf[c], s); \
    int wd = (round)*4 + w; \
    _Pragma("unroll") \
    for (int r = 0; r < 16; r++){ \
      int qr = (r&3) + 8*(r>>2) + 4*hh; \
      unsigned mw2 = bitsl[qr][wd]; \
      float av = ((mw2 >> l31) & 1u) ? __builtin_amdgcn_exp2f(s[r]) : 0.f; \
      shbuf[qr*132 + w*32 + l31] = av; \
    } \
    __syncthreads(); \
    _Pragma("unroll") \
    for (int rr = 0; rr < 4; rr++){ \
      int row = rr*8 + srow; \
      f32x4v v4 = *(const f32x4v*)(&shbuf[row*132 + scol]); \
      __builtin_nontemporal_store(v4, (f32x4v*)(abase + (long long)row*L_ + (round)*128 + scol)); \
    } \
    __syncthreads(); }

  LOADKF(kfA, w*32)
  #pragma unroll 1
  for (int round = 0; round < 16; round += 2){
    LOADKF(kfB, (round+1)*128 + w*32)
    P2BODY(round, kfA)
    if (round + 2 < 16) LOADKF(kfA, (round+2)*128 + w*32)
    P2BODY(round+1, kfB)
  }
#undef LOADKF
#undef P1BODY
#undef P2BODY
}

// ---------------- 4. FC GEMM: attf(frag bf16) @ wfcf(frag) -> fc (fp32 row-major) ----------------
__launch_bounds__(256, 4)
__global__ void k_fc(const short* __restrict__ attf, const short* __restrict__ wfcf,
                     float* __restrict__ fc){
  int t = threadIdx.x, w = t >> 6, l = t & 63, l31 = l & 31, hh = l >> 5;
  int mt = blockIdx.x*2 + (w & 1);
  int ntg = blockIdx.y*2 + (w >> 1);
  const short* ap = attf + (long long)mt * 16384 + l31*4;
  const short* bp = wfcf + (long long)ntg * 16384 + l31*4;
  f32x16 acc = {};
  for (int k0 = 0; k0 < DM_; k0 += 32){
    #pragma unroll
    for (int c = 0; c < 4; c++){
      short4v a = *(const short4v*)(ap + ((k0>>2) + 2*c + hh)*128);
      short4v b = *(const short4v*)(bp + ((k0>>2) + 2*c + hh)*128);
      acc = mfma_b(a, b, acc);
    }
  }
  #pragma unroll
  for (int r = 0; r < 16; r++){
    int m = mt*32 + (r&3) + 8*(r>>2) + 4*hh;
    fc[(long long)m*DM_ + ntg*32 + l31] = acc[r];
  }
}

// ---------------- 5. LayerNorm over [fc | residual q], gamma/beta ----------------
__global__ void k_ln(const float* __restrict__ fc, const float* __restrict__ qres,
                     const float* __restrict__ gamma, const float* __restrict__ beta,
                     float* __restrict__ out){
  int w = threadIdx.x >> 6, l = threadIdx.x & 63;
  int m = blockIdx.x*4 + w;
  const float* fr = fc   + (long long)m * DM_;
  const float* qr = qres + (long long)m * DQ_;
  float4 a0 = *(const float4*)(fr + l*8);
  float4 a1 = *(const float4*)(fr + l*8 + 4);
  float4 a2 = *(const float4*)(qr + l*4);
  float xv[12] = {a0.x,a0.y,a0.z,a0.w, a1.x,a1.y,a1.z,a1.w, a2.x,a2.y,a2.z,a2.w};
  float s = 0.f, ss = 0.f;
  #pragma unroll
  for (int i = 0; i < 12; i++){ s += xv[i]; ss += xv[i]*xv[i]; }
  #pragma unroll
  for (int off = 1; off < 64; off <<= 1){
    s  += __shfl_xor(s,  off, 64);
    ss += __shfl_xor(ss, off, 64);
  }
  const float inv768 = 1.0f/768.0f;
  float mu = s * inv768;
  float var = ss * inv768 - mu*mu;
  float rstd = 1.0f / sqrtf(var + 1e-6f);
  float4 g0 = *(const float4*)(gamma + l*8);
  float4 g1 = *(const float4*)(gamma + l*8 + 4);
  float4 g2 = *(const float4*)(gamma + 512 + l*4);
  float4 b0 = *(const float4*)(beta + l*8);
  float4 b1 = *(const float4*)(beta + l*8 + 4);
  float4 b2 = *(const float4*)(beta + 512 + l*4);
  float gv[12] = {g0.x,g0.y,g0.z,g0.w, g1.x,g1.y,g1.z,g1.w, g2.x,g2.y,g2.z,g2.w};
  float bv[12] = {b0.x,b0.y,b0.z,b0.w, b1.x,b1.y,b1.z,b1.w, b2.x,b2.y,b2.z,b2.w};
  float ov[12];
  #pragma unroll
  for (int i = 0; i < 12; i++) ov[i] = (xv[i] - mu)*rstd*gv[i] + bv[i];
  float* orow = out + (long long)m * (DM_ + DQ_);
  *(float4*)(orow + l*8)       = make_float4(ov[0], ov[1], ov[2],  ov[3]);
  *(float4*)(orow + l*8 + 4)   = make_float4(ov[4], ov[5], ov[6],  ov[7]);
  *(float4*)(orow + 512 + l*4) = make_float4(ov[8], ov[9], ov[10], ov[11]);
}

extern "C" void kernel_launch(void* const* d_in, const int* in_sizes, int n_in,
                              void* d_out, int out_size, void* d_ws, size_t ws_size,
                              hipStream_t stream){
  const float* q     = (const float*)d_in[0];
  const float* k     = (const float*)d_in[1];
  const float* v     = (const float*)d_in[2];
  const int*   mask  = (const int*)  d_in[3];
  const float* Wq    = (const float*)d_in[4];
  const float* Wk    = (const float*)d_in[5];
  const float* Wv    = (const float*)d_in[6];
  const float* Wfc   = (const float*)d_in[7];
  const float* gamma = (const float*)d_in[8];
  const float* beta  = (const float*)d_in[9];

  char* ws = (char*)d_ws;
  size_t off = 0;
  auto alloc = [&](size_t bytes)->void*{
    void* p = ws + off; off += (bytes + 255) & ~(size_t)255; return p;
  };
  unsigned long long* bits = (unsigned long long*)alloc((size_t)B_*L_*NKW*4);
  short* wqf    = (short*)alloc((size_t)DM_*DQ_*2);
  short* wkf    = (short*)alloc((size_t)DM_*DM_*2);
  short* wvf    = (short*)alloc((size_t)DM_*DM_*2);
  short* wfcf   = (short*)alloc((size_t)DM_*DM_*2);
  short* qh     = (short*)alloc((size_t)B_*H_*L_*DK_*2);
  short* kfr    = (short*)alloc((size_t)B_*H_*L_*DK_*2);
  short* vf     = (short*)alloc((size_t)B_*H_*L_*DK_*2);
  short* attf   = (short*)alloc((size_t)B_*L_*DM_*2);
  float* fc     = (float*)alloc((size_t)B_*L_*DM_*4);

  float* outp  = (float*)d_out;
  float* attnp = outp + (size_t)B_*L_*(DM_ + DQ_);

  { dim3 g(128, 4); k_wprep<<<g, 256, 0, stream>>>(Wq, Wk, Wv, Wfc, wqf, wkf, wvf, wfcf); }
  { dim3 g(128, 4); k_projmask<<<g, 256, 0, stream>>>(q, k, v, wqf, wkf, wvf, qh, kfr, vf, mask, bits); }
  k_attn<<<1024, 256, 0, stream>>>(qh, kfr, vf, (const unsigned*)bits, attf, attnp);
  { dim3 g(64, 8);  k_fc<<<g, 256, 0, stream>>>(attf, wfcf, fc); }
  k_ln<<<1024, 256, 0, stream>>>(fc, q, gamma, beta, outp);
}

// Round 12
// 151.009 us; speedup vs baseline: 1.1199x; 1.1199x over previous
//
#include <hip/hip_runtime.h>
#include <hip/hip_bf16.h>

#define B_ 2
#define L_ 2048
#define H_ 8
#define DK_ 64
#define DQ_ 256
#define DM_ 512
#define NKW 64                        // L_/32 mask words per row
#define QSCALE 0.18033688011112042f   // log2(e) / sqrt(D_K)

typedef short short4v __attribute__((ext_vector_type(4)));
typedef short short8v __attribute__((ext_vector_type(8)));
typedef float f32x16 __attribute__((ext_vector_type(16)));
typedef float f32x4v __attribute__((ext_vector_type(4)));
typedef unsigned long long u64x4 __attribute__((ext_vector_type(4)));

// RNE f32 -> bf16 (matches hardware/numpy; inputs here are never NaN/Inf)
__device__ __forceinline__ short f2bf(float f){
  unsigned u = __float_as_uint(f);
  unsigned r = (u + 0x7FFFu + ((u >> 16) & 1u)) >> 16;
  return (short)r;
}
__device__ __forceinline__ float bf2f(short s){
  return __uint_as_float(((unsigned)(unsigned short)s) << 16);
}

__device__ __forceinline__ f32x16 mfma_b(short4v a, short4v b, f32x16 c){
  // v_mfma_f32_32x32x8_bf16 (1k): A[i][k]: i=l%32, k=4*(l/32)+b
  // B[k][j]: j=l%32, k=4*(l/32)+b ; D[i][j]: j=l%32, i=(reg&3)+8*(reg>>2)+4*(l>>5)
  return __builtin_amdgcn_mfma_f32_32x32x8bf16_1k(a, b, c, 0, 0, 0);
}

// ---------------- 1. weights -> fragment-major bf16 ----------------
__global__ void k_wprep(const float* __restrict__ Wq, const float* __restrict__ Wk,
                        const float* __restrict__ Wv, const float* __restrict__ Wfc,
                        short* __restrict__ wqf, short* __restrict__ wkf,
                        short* __restrict__ wvf, short* __restrict__ wfcf){
  int which = blockIdx.y;
  const float* src; short* dst; int K, N;
  if (which == 0){ src = Wq;  dst = wqf;  K = DQ_; N = DM_; }
  else if (which == 1){ src = Wk;  dst = wkf;  K = DM_; N = DM_; }
  else if (which == 2){ src = Wv;  dst = wvf;  K = DM_; N = DM_; }
  else { src = Wfc; dst = wfcf; K = DM_; N = DM_; }
  int K4 = K >> 2;
  long long e0 = ((long long)blockIdx.x * 256 + threadIdx.x) * 8;
  if (e0 >= (long long)K * N) return;
  short8v o;
  #pragma unroll
  for (int u = 0; u < 8; u++){
    long long e = e0 + u;
    int km = (int)(e & 3), j = (int)((e >> 2) & 31);
    int rest = (int)(e >> 7);
    int k4 = rest % K4, nt = rest / K4;
    o[u] = f2bf(src[(long long)(k4*4 + km)*N + nt*32 + j]);
  }
  *(short8v*)(dst + e0) = o;
}

// ---------------- 2. QKV projection GEMM (y<3, x<128) + mask bit-pack (y==3, all x) ----------------
// qh: row-major [bh][lq][dk]
// kfr: [bh][kt=key/32][dk4][j=key%32][dk%4]
// vf:  [bh][key4=key/4][dv][key%4]
__launch_bounds__(256, 4)
__global__ void k_projmask(const float* __restrict__ qs, const float* __restrict__ ks, const float* __restrict__ vs,
                           const short* __restrict__ wqf, const short* __restrict__ wkf, const short* __restrict__ wvf,
                           short* __restrict__ qh, short* __restrict__ kfr, short* __restrict__ vf,
                           const int* __restrict__ mask, unsigned long long* __restrict__ bits){
  int which = blockIdx.y;
  if (which == 3){
    // mask pack: memory-bound; gets the full 512-block grid for concurrency
    const long long nwords = (long long)B_ * L_ * L_ / 64;
    int l = threadIdx.x & 63;
    long long wid = ((long long)blockIdx.x * 256 + threadIdx.x) >> 6;
    long long nw  = ((long long)gridDim.x * 256) >> 6;
    for (long long w0 = wid * 4; w0 < nwords; w0 += nw * 4){
      const int* p = mask + w0 * 64 + l;
      unsigned long long b0 = __ballot(p[0]   != 0);
      unsigned long long b1 = __ballot(p[64]  != 0);
      unsigned long long b2 = __ballot(p[128] != 0);
      unsigned long long b3 = __ballot(p[192] != 0);
      if (l == 0){
        u64x4 o; o.x = b0; o.y = b1; o.z = b2; o.w = b3;
        *(u64x4*)(bits + w0) = o;
      }
    }
    return;
  }
  if (blockIdx.x >= 128) return;             // proj uses only 128 x-blocks
  const float* src; const short* wt; int K; float scale;
  if (which == 0){ src = qs; wt = wqf; K = DQ_; scale = QSCALE; }
  else if (which == 1){ src = ks; wt = wkf; K = DM_; scale = 1.f; }
  else { src = vs; wt = wvf; K = DM_; scale = 1.f; }
  int K4 = K >> 2;

  int t = threadIdx.x, w = t >> 6, l = t & 63, l31 = l & 31, hh = l >> 5;
  int m0 = blockIdx.x * 32;
  const float* arow = src + (long long)(m0 + l31) * K + 4*hh;

  f32x16 acc[4] = {};
  for (int k0 = 0; k0 < K; k0 += 32){
    short4v af[4];
    #pragma unroll
    for (int c = 0; c < 4; c++){
      float4 a4 = *(const float4*)(arow + k0 + 8*c);
      af[c].x = f2bf(a4.x); af[c].y = f2bf(a4.y); af[c].z = f2bf(a4.z); af[c].w = f2bf(a4.w);
    }
    #pragma unroll
    for (int c = 0; c < 4; c++){
      #pragma unroll
      for (int nt = 0; nt < 4; nt++){
        int ntg = w*4 + nt;
        const short* bp = wt + ((long long)(ntg*K4 + (k0>>2) + 2*c + hh)*32 + l31)*4;
        acc[nt] = mfma_b(af[c], *(const short4v*)bp, acc[nt]);
      }
    }
  }

  if (which == 0){
    #pragma unroll
    for (int nt = 0; nt < 4; nt++){
      int n = (w*4 + nt)*32 + l31;
      int h_ = n >> 6, dk = n & 63;
      #pragma unroll
      for (int r = 0; r < 16; r++){
        int m = m0 + (r&3) + 8*(r>>2) + 4*hh;
        int b = m >> 11, lq = m & 2047;
        qh[((long long)(b*H_ + h_)*L_ + lq)*DK_ + dk] = f2bf(acc[nt][r] * scale);
      }
    }
  } else if (which == 1){
    #pragma unroll
    for (int nt = 0; nt < 4; nt++){
      int n = (w*4 + nt)*32 + l31;
      int h_ = n >> 6, dk = n & 63;
      #pragma unroll
      for (int r = 0; r < 16; r++){
        int m = m0 + (r&3) + 8*(r>>2) + 4*hh;
        int b = m >> 11, lq = m & 2047;
        long long idx = ((((long long)(b*H_ + h_)*64 + (lq>>5))*16 + (dk>>2))*32 + (lq&31))*4 + (dk&3);
        kfr[idx] = f2bf(acc[nt][r]);
      }
    }
  } else {
    #pragma unroll
    for (int nt = 0; nt < 4; nt++){
      int n = (w*4 + nt)*32 + l31;
      int h_ = n >> 6, dv = n & 63;
      #pragma unroll
      for (int rg = 0; rg < 4; rg++){
        int m = m0 + 8*rg + 4*hh;
        int b = m >> 11, lq = m & 2047;
        short4v o;
        o.x = f2bf(acc[nt][4*rg+0]); o.y = f2bf(acc[nt][4*rg+1]);
        o.z = f2bf(acc[nt][4*rg+2]); o.w = f2bf(acc[nt][4*rg+3]);
        long long idx = (((long long)(b*H_ + h_)*512 + (lq>>2))*64 + dv)*4;
        *(short4v*)(vf + idx) = o;
      }
    }
  }
}

// ---------------- 3. merged attention: pass1 S^T+PV+rowsum -> attf; pass2 S -> normalized attn NT store ----------------
// (exact R10 form — register prefetch regressed in R11 via VGPR pressure)
__launch_bounds__(256, 4)
__global__ void k_attn(const short* __restrict__ qh, const short* __restrict__ kfr,
                       const short* __restrict__ vf, const unsigned* __restrict__ bits,
                       short* __restrict__ attf, float* __restrict__ attn){
  __shared__ unsigned bitsl[32][65];
  __shared__ float rs[4][32];
  __shared__ float inv_l[32];
  __shared__ float shbuf[4608];        // pvb: (w*32+qr)*36+i ; tile: row*132+col

  int wg = blockIdx.x;
  wg = (wg & 7) * 128 + (wg >> 3);     // XCD-chunked swizzle (1024 % 8 == 0)
  int qt = wg & 63, bh = wg >> 6;
  int b = bh >> 3, h_ = bh & 7;
  int q0 = qt * 32;
  int t = threadIdx.x, w = t >> 6, l = t & 63, l31 = l & 31, hh = l >> 5;

  for (int i = t; i < 32 * 64; i += 256){
    int qq = i >> 6, wd = i & 63;
    bitsl[qq][wd] = bits[(long long)(b*L_ + q0 + qq)*NKW + wd];
  }

  const short* qbase = qh  + ((long long)bh*L_ + q0 + l31) * DK_;
  const short* kbase = kfr + (long long)bh * L_ * DK_;
  const short* vbase = vf  + (long long)bh * L_ * DK_;

  short4v qf[8];
  #pragma unroll
  for (int c = 0; c < 8; c++) qf[c] = *(const short4v*)(qbase + 8*c + 4*hh);

  __syncthreads();

  // ---- pass 1: S^T = mfma(K,Q); lane owns q-column; e regs feed PV A-frag directly
  f32x16 pv0 = {}, pv1 = {};
  float rowsum = 0.f;

  #pragma unroll 1
  for (int tt = 0; tt < 16; tt++){
    int k0 = w*512 + tt*32;
    const short* kp = kbase + (long long)(k0 >> 5) * 2048 + l31*4;
    short4v kf[8];
    #pragma unroll
    for (int c = 0; c < 8; c++) kf[c] = *(const short4v*)(kp + (2*c + hh)*128);
    f32x16 s = {};
    #pragma unroll
    for (int c = 0; c < 8; c++) s = mfma_b(kf[c], qf[c], s);
    unsigned mw = bitsl[l31][k0 >> 5];
    #pragma unroll
    for (int j = 0; j < 4; j++){
      short4v a;
      #pragma unroll
      for (int i = 0; i < 4; i++){
        float ev = __builtin_amdgcn_exp2f(s[4*j + i]);
        ev = ((mw >> (i + 8*j + 4*hh)) & 1u) ? ev : 0.f;
        rowsum += ev;
        a[i] = f2bf(ev);
      }
      const short* vp = vbase + (long long)((k0>>2) + 2*j + hh) * 256;
      short4v v0 = *(const short4v*)(vp + l31*4);
      short4v v1 = *(const short4v*)(vp + (32 + l31)*4);
      pv0 = mfma_b(a, v0, pv0);
      pv1 = mfma_b(a, v1, pv1);
    }
  }

  rowsum += __shfl_xor(rowsum, 32, 64);
  if (l < 32) rs[w][l] = rowsum;
  __syncthreads();

  long long mtbase = (long long)((b*L_ + q0) >> 5) * 16384;

  // round A: reduce pv0 (dv 0..31)
  #pragma unroll
  for (int r = 0; r < 16; r++){
    int qr = (r&3) + 8*(r>>2) + 4*hh;
    shbuf[(w*32 + qr)*36 + l31] = pv0[r];
  }
  if (t < 32) inv_l[t] = 1.f / (rs[0][t] + rs[1][t] + rs[2][t] + rs[3][t]);
  __syncthreads();
  {
    int qq = t >> 3, dv0 = (t & 7) * 4;
    float iq = inv_l[qq];
    float a0=0,a1=0,a2=0,a3=0;
    #pragma unroll
    for (int ww = 0; ww < 4; ww++){
      const float* pb = &shbuf[(ww*32 + qq)*36 + dv0];
      a0 += pb[0]; a1 += pb[1]; a2 += pb[2]; a3 += pb[3];
    }
    short4v o; o.x = f2bf(a0*iq); o.y = f2bf(a1*iq); o.z = f2bf(a2*iq); o.w = f2bf(a3*iq);
    *(short4v*)(attf + mtbase + ((long long)(h_*16 + (t&7))*32 + qq)*4) = o;
  }
  __syncthreads();

  // round B: reduce pv1 (dv 32..63)
  #pragma unroll
  for (int r = 0; r < 16; r++){
    int qr = (r&3) + 8*(r>>2) + 4*hh;
    shbuf[(w*32 + qr)*36 + l31] = pv1[r];
  }
  __syncthreads();
  {
    int qq = t >> 3, dv0 = (t & 7) * 4;
    float iq = inv_l[qq];
    float a0=0,a1=0,a2=0,a3=0;
    #pragma unroll
    for (int ww = 0; ww < 4; ww++){
      const float* pb = &shbuf[(ww*32 + qq)*36 + dv0];
      a0 += pb[0]; a1 += pb[1]; a2 += pb[2]; a3 += pb[3];
    }
    short4v o; o.x = f2bf(a0*iq); o.y = f2bf(a1*iq); o.z = f2bf(a2*iq); o.w = f2bf(a3*iq);
    *(short4v*)(attf + mtbase + ((long long)(h_*16 + 8 + (t&7))*32 + qq)*4) = o;
  }
  __syncthreads();                     // pvb readers done before shbuf becomes tile

  // ---- pass 2: S = mfma(Q,K), C-init = log2(inv) => exp2 yields normalized attn; NT store
  f32x16 linv;
  #pragma unroll
  for (int r = 0; r < 16; r++) linv[r] = __log2f(inv_l[(r&3) + 8*(r>>2) + 4*hh]);

  float* abase = attn + ((long long)bh*L_ + q0) * L_;
  int srow = t >> 5, scol = (t & 31) * 4;

  #pragma unroll 1
  for (int round = 0; round < 16; round++){
    int k0 = round*128 + w*32;
    const short* kp = kbase + (long long)(k0 >> 5) * 2048 + l31*4;
    short4v kf[8];
    #pragma unroll
    for (int c = 0; c < 8; c++) kf[c] = *(const short4v*)(kp + (2*c + hh)*128);
    f32x16 s = linv;
    #pragma unroll
    for (int c = 0; c < 8; c++) s = mfma_b(qf[c], kf[c], s);
    int wd = round*4 + w;
    #pragma unroll
    for (int r = 0; r < 16; r++){
      int qr = (r&3) + 8*(r>>2) + 4*hh;
      unsigned mw2 = bitsl[qr][wd];
      float av = ((mw2 >> l31) & 1u) ? __builtin_amdgcn_exp2f(s[r]) : 0.f;
      shbuf[qr*132 + w*32 + l31] = av;
    }
    __syncthreads();
    #pragma unroll
    for (int rr = 0; rr < 4; rr++){
      int row = rr*8 + srow;
      f32x4v v4 = *(const f32x4v*)(&shbuf[row*132 + scol]);
      __builtin_nontemporal_store(v4, (f32x4v*)(abase + (long long)row*L_ + round*128 + scol));
    }
    __syncthreads();
  }
}

// ---------------- 4. FC GEMM: attf(frag bf16) @ wfcf(frag) -> fc (fp32 row-major) ----------------
__launch_bounds__(256, 4)
__global__ void k_fc(const short* __restrict__ attf, const short* __restrict__ wfcf,
                     float* __restrict__ fc){
  int t = threadIdx.x, w = t >> 6, l = t & 63, l31 = l & 31, hh = l >> 5;
  int mt = blockIdx.x*2 + (w & 1);
  int ntg = blockIdx.y*2 + (w >> 1);
  const short* ap = attf + (long long)mt * 16384 + l31*4;
  const short* bp = wfcf + (long long)ntg * 16384 + l31*4;
  f32x16 acc = {};
  for (int k0 = 0; k0 < DM_; k0 += 32){
    #pragma unroll
    for (int c = 0; c < 4; c++){
      short4v a = *(const short4v*)(ap + ((k0>>2) + 2*c + hh)*128);
      short4v b = *(const short4v*)(bp + ((k0>>2) + 2*c + hh)*128);
      acc = mfma_b(a, b, acc);
    }
  }
  #pragma unroll
  for (int r = 0; r < 16; r++){
    int m = mt*32 + (r&3) + 8*(r>>2) + 4*hh;
    fc[(long long)m*DM_ + ntg*32 + l31] = acc[r];
  }
}

// ---------------- 5. LayerNorm over [fc | residual q], gamma/beta ----------------
__global__ void k_ln(const float* __restrict__ fc, const float* __restrict__ qres,
                     const float* __restrict__ gamma, const float* __restrict__ beta,
                     float* __restrict__ out){
  int w = threadIdx.x >> 6, l = threadIdx.x & 63;
  int m = blockIdx.x*4 + w;
  const float* fr = fc   + (long long)m * DM_;
  const float* qr = qres + (long long)m * DQ_;
  float4 a0 = *(const float4*)(fr + l*8);
  float4 a1 = *(const float4*)(fr + l*8 + 4);
  float4 a2 = *(const float4*)(qr + l*4);
  float xv[12] = {a0.x,a0.y,a0.z,a0.w, a1.x,a1.y,a1.z,a1.w, a2.x,a2.y,a2.z,a2.w};
  float s = 0.f, ss = 0.f;
  #pragma unroll
  for (int i = 0; i < 12; i++){ s += xv[i]; ss += xv[i]*xv[i]; }
  #pragma unroll
  for (int off = 1; off < 64; off <<= 1){
    s  += __shfl_xor(s,  off, 64);
    ss += __shfl_xor(ss, off, 64);
  }
  const float inv768 = 1.0f/768.0f;
  float mu = s * inv768;
  float var = ss * inv768 - mu*mu;
  float rstd = 1.0f / sqrtf(var + 1e-6f);
  float4 g0 = *(const float4*)(gamma + l*8);
  float4 g1 = *(const float4*)(gamma + l*8 + 4);
  float4 g2 = *(const float4*)(gamma + 512 + l*4);
  float4 b0 = *(const float4*)(beta + l*8);
  float4 b1 = *(const float4*)(beta + l*8 + 4);
  float4 b2 = *(const float4*)(beta + 512 + l*4);
  float gv[12] = {g0.x,g0.y,g0.z,g0.w, g1.x,g1.y,g1.z,g1.w, g2.x,g2.y,g2.z,g2.w};
  float bv[12] = {b0.x,b0.y,b0.z,b0.w, b1.x,b1.y,b1.z,b1.w, b2.x,b2.y,b2.z,b2.w};
  float ov[12];
  #pragma unroll
  for (int i = 0; i < 12; i++) ov[i] = (xv[i] - mu)*rstd*gv[i] + bv[i];
  float* orow = out + (long long)m * (DM_ + DQ_);
  *(float4*)(orow + l*8)       = make_float4(ov[0], ov[1], ov[2],  ov[3]);
  *(float4*)(orow + l*8 + 4)   = make_float4(ov[4], ov[5], ov[6],  ov[7]);
  *(float4*)(orow + 512 + l*4) = make_float4(ov[8], ov[9], ov[10], ov[11]);
}

extern "C" void kernel_launch(void* const* d_in, const int* in_sizes, int n_in,
                              void* d_out, int out_size, void* d_ws, size_t ws_size,
                              hipStream_t stream){
  const float* q     = (const float*)d_in[0];
  const float* k     = (const float*)d_in[1];
  const float* v     = (const float*)d_in[2];
  const int*   mask  = (const int*)  d_in[3];
  const float* Wq    = (const float*)d_in[4];
  const float* Wk    = (const float*)d_in[5];
  const float* Wv    = (const float*)d_in[6];
  const float* Wfc   = (const float*)d_in[7];
  const float* gamma = (const float*)d_in[8];
  const float* beta  = (const float*)d_in[9];

  char* ws = (char*)d_ws;
  size_t off = 0;
  auto alloc = [&](size_t bytes)->void*{
    void* p = ws + off; off += (bytes + 255) & ~(size_t)255; return p;
  };
  unsigned long long* bits = (unsigned long long*)alloc((size_t)B_*L_*NKW*4);
  short* wqf    = (short*)alloc((size_t)DM_*DQ_*2);
  short* wkf    = (short*)alloc((size_t)DM_*DM_*2);
  short* wvf    = (short*)alloc((size_t)DM_*DM_*2);
  short* wfcf   = (short*)alloc((size_t)DM_*DM_*2);
  short* qh     = (short*)alloc((size_t)B_*H_*L_*DK_*2);
  short* kfr    = (short*)alloc((size_t)B_*H_*L_*DK_*2);
  short* vf     = (short*)alloc((size_t)B_*H_*L_*DK_*2);
  short* attf   = (short*)alloc((size_t)B_*L_*DM_*2);
  float* fc     = (float*)alloc((size_t)B_*L_*DM_*4);

  float* outp  = (float*)d_out;
  float* attnp = outp + (size_t)B_*L_*(DM_ + DQ_);

  { dim3 g(128, 4); k_wprep<<<g, 256, 0, stream>>>(Wq, Wk, Wv, Wfc, wqf, wkf, wvf, wfcf); }
  { dim3 g(512, 4); k_projmask<<<g, 256, 0, stream>>>(q, k, v, wqf, wkf, wvf, qh, kfr, vf, mask, bits); }
  k_attn<<<1024, 256, 0, stream>>>(qh, kfr, vf, (const unsigned*)bits, attf, attnp);
  { dim3 g(64, 8);  k_fc<<<g, 256, 0, stream>>>(attf, wfcf, fc); }
  k_ln<<<1024, 256, 0, stream>>>(fc, q, gamma, beta, outp);
}

// Round 13
// 139.972 us; speedup vs baseline: 1.2082x; 1.0789x over previous
//
#include <hip/hip_runtime.h>
#include <hip/hip_bf16.h>

#define B_ 2
#define L_ 2048
#define H_ 8
#define DK_ 64
#define DQ_ 256
#define DM_ 512
#define NKW 64                        // L_/32 mask words per row
#define QSCALE 0.18033688011112042f   // log2(e) / sqrt(D_K)

typedef short short4v __attribute__((ext_vector_type(4)));
typedef short short8v __attribute__((ext_vector_type(8)));
typedef float f32x16 __attribute__((ext_vector_type(16)));
typedef float f32x4v __attribute__((ext_vector_type(4)));
typedef unsigned long long u64x4 __attribute__((ext_vector_type(4)));

// RNE f32 -> bf16 (matches hardware/numpy; inputs here are never NaN/Inf)
__device__ __forceinline__ short f2bf(float f){
  unsigned u = __float_as_uint(f);
  unsigned r = (u + 0x7FFFu + ((u >> 16) & 1u)) >> 16;
  return (short)r;
}
__device__ __forceinline__ float bf2f(short s){
  return __uint_as_float(((unsigned)(unsigned short)s) << 16);
}

__device__ __forceinline__ f32x16 mfma_b(short4v a, short4v b, f32x16 c){
  // v_mfma_f32_32x32x8_bf16 (1k): A[i][k]: i=l%32, k=4*(l/32)+b
  // B[k][j]: j=l%32, k=4*(l/32)+b ; D[i][j]: j=l%32, i=(reg&3)+8*(reg>>2)+4*(l>>5)
  return __builtin_amdgcn_mfma_f32_32x32x8bf16_1k(a, b, c, 0, 0, 0);
}

// ---------------- 1. weights -> fragment-major bf16 ----------------
__global__ void k_wprep(const float* __restrict__ Wq, const float* __restrict__ Wk,
                        const float* __restrict__ Wv, const float* __restrict__ Wfc,
                        short* __restrict__ wqf, short* __restrict__ wkf,
                        short* __restrict__ wvf, short* __restrict__ wfcf){
  int which = blockIdx.y;
  const float* src; short* dst; int K, N;
  if (which == 0){ src = Wq;  dst = wqf;  K = DQ_; N = DM_; }
  else if (which == 1){ src = Wk;  dst = wkf;  K = DM_; N = DM_; }
  else if (which == 2){ src = Wv;  dst = wvf;  K = DM_; N = DM_; }
  else { src = Wfc; dst = wfcf; K = DM_; N = DM_; }
  int K4 = K >> 2;
  long long e0 = ((long long)blockIdx.x * 256 + threadIdx.x) * 8;
  if (e0 >= (long long)K * N) return;
  short8v o;
  #pragma unroll
  for (int u = 0; u < 8; u++){
    long long e = e0 + u;
    int km = (int)(e & 3), j = (int)((e >> 2) & 31);
    int rest = (int)(e >> 7);
    int k4 = rest % K4, nt = rest / K4;
    o[u] = f2bf(src[(long long)(k4*4 + km)*N + nt*32 + j]);
  }
  *(short8v*)(dst + e0) = o;
}

// ---------------- 2. QKV projection GEMM (y<3) + mask bit-pack (y==3) ----------------
// qh: row-major [bh][lq][dk]
// kfr: [bh][kt=key/32][dk4][j=key%32][dk%4]
// vf:  [bh][key4=key/4][dv][key%4]
__launch_bounds__(256, 4)
__global__ void k_projmask(const float* __restrict__ qs, const float* __restrict__ ks, const float* __restrict__ vs,
                           const short* __restrict__ wqf, const short* __restrict__ wkf, const short* __restrict__ wvf,
                           short* __restrict__ qh, short* __restrict__ kfr, short* __restrict__ vf,
                           const int* __restrict__ mask, unsigned long long* __restrict__ bits){
  int which = blockIdx.y;
  if (which == 3){
    // mask pack: memory-bound, overlaps with compute-bound proj blocks
    const long long nwords = (long long)B_ * L_ * L_ / 64;
    int l = threadIdx.x & 63;
    long long wid = ((long long)blockIdx.x * 256 + threadIdx.x) >> 6;
    long long nw  = ((long long)gridDim.x * 256) >> 6;
    for (long long w0 = wid * 4; w0 < nwords; w0 += nw * 4){
      const int* p = mask + w0 * 64 + l;
      unsigned long long b0 = __ballot(p[0]   != 0);
      unsigned long long b1 = __ballot(p[64]  != 0);
      unsigned long long b2 = __ballot(p[128] != 0);
      unsigned long long b3 = __ballot(p[192] != 0);
      if (l == 0){
        u64x4 o; o.x = b0; o.y = b1; o.z = b2; o.w = b3;
        *(u64x4*)(bits + w0) = o;
      }
    }
    return;
  }
  const float* src; const short* wt; int K; float scale;
  if (which == 0){ src = qs; wt = wqf; K = DQ_; scale = QSCALE; }
  else if (which == 1){ src = ks; wt = wkf; K = DM_; scale = 1.f; }
  else { src = vs; wt = wvf; K = DM_; scale = 1.f; }
  int K4 = K >> 2;

  int t = threadIdx.x, w = t >> 6, l = t & 63, l31 = l & 31, hh = l >> 5;
  int m0 = blockIdx.x * 32;
  const float* arow = src + (long long)(m0 + l31) * K + 4*hh;

  f32x16 acc[4] = {};
  for (int k0 = 0; k0 < K; k0 += 32){
    short4v af[4];
    #pragma unroll
    for (int c = 0; c < 4; c++){
      float4 a4 = *(const float4*)(arow + k0 + 8*c);
      af[c].x = f2bf(a4.x); af[c].y = f2bf(a4.y); af[c].z = f2bf(a4.z); af[c].w = f2bf(a4.w);
    }
    #pragma unroll
    for (int c = 0; c < 4; c++){
      #pragma unroll
      for (int nt = 0; nt < 4; nt++){
        int ntg = w*4 + nt;
        const short* bp = wt + ((long long)(ntg*K4 + (k0>>2) + 2*c + hh)*32 + l31)*4;
        acc[nt] = mfma_b(af[c], *(const short4v*)bp, acc[nt]);
      }
    }
  }

  if (which == 0){
    #pragma unroll
    for (int nt = 0; nt < 4; nt++){
      int n = (w*4 + nt)*32 + l31;
      int h_ = n >> 6, dk = n & 63;
      #pragma unroll
      for (int r = 0; r < 16; r++){
        int m = m0 + (r&3) + 8*(r>>2) + 4*hh;
        int b = m >> 11, lq = m & 2047;
        qh[((long long)(b*H_ + h_)*L_ + lq)*DK_ + dk] = f2bf(acc[nt][r] * scale);
      }
    }
  } else if (which == 1){
    #pragma unroll
    for (int nt = 0; nt < 4; nt++){
      int n = (w*4 + nt)*32 + l31;
      int h_ = n >> 6, dk = n & 63;
      #pragma unroll
      for (int r = 0; r < 16; r++){
        int m = m0 + (r&3) + 8*(r>>2) + 4*hh;
        int b = m >> 11, lq = m & 2047;
        long long idx = ((((long long)(b*H_ + h_)*64 + (lq>>5))*16 + (dk>>2))*32 + (lq&31))*4 + (dk&3);
        kfr[idx] = f2bf(acc[nt][r]);
      }
    }
  } else {
    #pragma unroll
    for (int nt = 0; nt < 4; nt++){
      int n = (w*4 + nt)*32 + l31;
      int h_ = n >> 6, dv = n & 63;
      #pragma unroll
      for (int rg = 0; rg < 4; rg++){
        int m = m0 + 8*rg + 4*hh;
        int b = m >> 11, lq = m & 2047;
        short4v o;
        o.x = f2bf(acc[nt][4*rg+0]); o.y = f2bf(acc[nt][4*rg+1]);
        o.z = f2bf(acc[nt][4*rg+2]); o.w = f2bf(acc[nt][4*rg+3]);
        long long idx = (((long long)(b*H_ + h_)*512 + (lq>>2))*64 + dv)*4;
        *(short4v*)(vf + idx) = o;
      }
    }
  }
}

// ---------------- 3. merged attention: pass1 S^T+PV+rowsum -> attf; pass2 S -> normalized attn NT store ----------------
// LDS union: shbuf serves as pvb[4][32][36] (PV reduce) then tile[32][132] (store staging). 27.4KB -> 4 blocks/CU
// grid 1024 @ 4/CU = exactly one full residency wave.
__launch_bounds__(256, 4)
__global__ void k_attn(const short* __restrict__ qh, const short* __restrict__ kfr,
                       const short* __restrict__ vf, const unsigned* __restrict__ bits,
                       short* __restrict__ attf, float* __restrict__ attn){
  __shared__ unsigned bitsl[32][65];
  __shared__ float rs[4][32];
  __shared__ float inv_l[32];
  __shared__ float shbuf[4608];        // pvb: (w*32+qr)*36+i ; tile: row*132+col

  int wg = blockIdx.x;
  wg = (wg & 7) * 128 + (wg >> 3);     // XCD-chunked swizzle (1024 % 8 == 0)
  int qt = wg & 63, bh = wg >> 6;
  int b = bh >> 3, h_ = bh & 7;
  int q0 = qt * 32;
  int t = threadIdx.x, w = t >> 6, l = t & 63, l31 = l & 31, hh = l >> 5;

  for (int i = t; i < 32 * 64; i += 256){
    int qq = i >> 6, wd = i & 63;
    bitsl[qq][wd] = bits[(long long)(b*L_ + q0 + qq)*NKW + wd];
  }

  const short* qbase = qh  + ((long long)bh*L_ + q0 + l31) * DK_;
  const short* kbase = kfr + (long long)bh * L_ * DK_;
  const short* vbase = vf  + (long long)bh * L_ * DK_;

  short4v qf[8];
  #pragma unroll
  for (int c = 0; c < 8; c++) qf[c] = *(const short4v*)(qbase + 8*c + 4*hh);

  __syncthreads();

  // ---- pass 1: S^T = mfma(K,Q); lane owns q-column; e regs feed PV A-frag directly
  f32x16 pv0 = {}, pv1 = {};
  float rowsum = 0.f;

  #pragma unroll 1
  for (int tt = 0; tt < 16; tt++){
    int k0 = w*512 + tt*32;
    const short* kp = kbase + (long long)(k0 >> 5) * 2048 + l31*4;
    short4v kf[8];
    #pragma unroll
    for (int c = 0; c < 8; c++) kf[c] = *(const short4v*)(kp + (2*c + hh)*128);
    f32x16 s = {};
    #pragma unroll
    for (int c = 0; c < 8; c++) s = mfma_b(kf[c], qf[c], s);
    unsigned mw = bitsl[l31][k0 >> 5];
    #pragma unroll
    for (int j = 0; j < 4; j++){
      short4v a;
      #pragma unroll
      for (int i = 0; i < 4; i++){
        float ev = __builtin_amdgcn_exp2f(s[4*j + i]);
        ev = ((mw >> (i + 8*j + 4*hh)) & 1u) ? ev : 0.f;
        rowsum += ev;
        a[i] = f2bf(ev);
      }
      const short* vp = vbase + (long long)((k0>>2) + 2*j + hh) * 256;
      short4v v0 = *(const short4v*)(vp + l31*4);
      short4v v1 = *(const short4v*)(vp + (32 + l31)*4);
      pv0 = mfma_b(a, v0, pv0);
      pv1 = mfma_b(a, v1, pv1);
    }
  }

  rowsum += __shfl_xor(rowsum, 32, 64);
  if (l < 32) rs[w][l] = rowsum;
  __syncthreads();

  long long mtbase = (long long)((b*L_ + q0) >> 5) * 16384;

  // round A: reduce pv0 (dv 0..31)
  #pragma unroll
  for (int r = 0; r < 16; r++){
    int qr = (r&3) + 8*(r>>2) + 4*hh;
    shbuf[(w*32 + qr)*36 + l31] = pv0[r];
  }
  if (t < 32) inv_l[t] = 1.f / (rs[0][t] + rs[1][t] + rs[2][t] + rs[3][t]);
  __syncthreads();
  {
    int qq = t >> 3, dv0 = (t & 7) * 4;
    float iq = inv_l[qq];
    float a0=0,a1=0,a2=0,a3=0;
    #pragma unroll
    for (int ww = 0; ww < 4; ww++){
      const float* pb = &shbuf[(ww*32 + qq)*36 + dv0];
      a0 += pb[0]; a1 += pb[1]; a2 += pb[2]; a3 += pb[3];
    }
    short4v o; o.x = f2bf(a0*iq); o.y = f2bf(a1*iq); o.z = f2bf(a2*iq); o.w = f2bf(a3*iq);
    *(short4v*)(attf + mtbase + ((long long)(h_*16 + (t&7))*32 + qq)*4) = o;
  }
  __syncthreads();

  // round B: reduce pv1 (dv 32..63)
  #pragma unroll
  for (int r = 0; r < 16; r++){
    int qr = (r&3) + 8*(r>>2) + 4*hh;
    shbuf[(w*32 + qr)*36 + l31] = pv1[r];
  }
  __syncthreads();
  {
    int qq = t >> 3, dv0 = (t & 7) * 4;
    float iq = inv_l[qq];
    float a0=0,a1=0,a2=0,a3=0;
    #pragma unroll
    for (int ww = 0; ww < 4; ww++){
      const float* pb = &shbuf[(ww*32 + qq)*36 + dv0];
      a0 += pb[0]; a1 += pb[1]; a2 += pb[2]; a3 += pb[3];
    }
    short4v o; o.x = f2bf(a0*iq); o.y = f2bf(a1*iq); o.z = f2bf(a2*iq); o.w = f2bf(a3*iq);
    *(short4v*)(attf + mtbase + ((long long)(h_*16 + 8 + (t&7))*32 + qq)*4) = o;
  }
  __syncthreads();                     // pvb readers done before shbuf becomes tile

  // ---- pass 2: S = mfma(Q,K), C-init = log2(inv) => exp2 yields normalized attn; NT store
  f32x16 linv;
  #pragma unroll
  for (int r = 0; r < 16; r++) linv[r] = __log2f(inv_l[(r&3) + 8*(r>>2) + 4*hh]);

  float* abase = attn + ((long long)bh*L_ + q0) * L_;
  int srow = t >> 5, scol = (t & 31) * 4;

  #pragma unroll 1
  for (int round = 0; round < 16; round++){
    int k0 = round*128 + w*32;
    const short* kp = kbase + (long long)(k0 >> 5) * 2048 + l31*4;
    short4v kf[8];
    #pragma unroll
    for (int c = 0; c < 8; c++) kf[c] = *(const short4v*)(kp + (2*c + hh)*128);
    f32x16 s = linv;
    #pragma unroll
    for (int c = 0; c < 8; c++) s = mfma_b(qf[c], kf[c], s);
    int wd = round*4 + w;
    #pragma unroll
    for (int r = 0; r < 16; r++){
      int qr = (r&3) + 8*(r>>2) + 4*hh;
      unsigned mw2 = bitsl[qr][wd];
      float av = ((mw2 >> l31) & 1u) ? __builtin_amdgcn_exp2f(s[r]) : 0.f;
      shbuf[qr*132 + w*32 + l31] = av;
    }
    __syncthreads();
    #pragma unroll
    for (int rr = 0; rr < 4; rr++){
      int row = rr*8 + srow;
      f32x4v v4 = *(const f32x4v*)(&shbuf[row*132 + scol]);
      __builtin_nontemporal_store(v4, (f32x4v*)(abase + (long long)row*L_ + round*128 + scol));
    }
    __syncthreads();
  }
}

// ---------------- 4. FC GEMM: attf(frag bf16) @ wfcf(frag) -> fc (fp32 row-major) ----------------
__launch_bounds__(256, 4)
__global__ void k_fc(const short* __restrict__ attf, const short* __restrict__ wfcf,
                     float* __restrict__ fc){
  int t = threadIdx.x, w = t >> 6, l = t & 63, l31 = l & 31, hh = l >> 5;
  int mt = blockIdx.x*2 + (w & 1);
  int ntg = blockIdx.y*2 + (w >> 1);
  const short* ap = attf + (long long)mt * 16384 + l31*4;
  const short* bp = wfcf + (long long)ntg * 16384 + l31*4;
  f32x16 acc = {};
  for (int k0 = 0; k0 < DM_; k0 += 32){
    #pragma unroll
    for (int c = 0; c < 4; c++){
      short4v a = *(const short4v*)(ap + ((k0>>2) + 2*c + hh)*128);
      short4v b = *(const short4v*)(bp + ((k0>>2) + 2*c + hh)*128);
      acc = mfma_b(a, b, acc);
    }
  }
  #pragma unroll
  for (int r = 0; r < 16; r++){
    int m = mt*32 + (r&3) + 8*(r>>2) + 4*hh;
    fc[(long long)m*DM_ + ntg*32 + l31] = acc[r];
  }
}

// ---------------- 5. LayerNorm over [fc | residual q], gamma/beta ----------------
__global__ void k_ln(const float* __restrict__ fc, const float* __restrict__ qres,
                     const float* __restrict__ gamma, const float* __restrict__ beta,
                     float* __restrict__ out){
  int w = threadIdx.x >> 6, l = threadIdx.x & 63;
  int m = blockIdx.x*4 + w;
  const float* fr = fc   + (long long)m * DM_;
  const float* qr = qres + (long long)m * DQ_;
  float4 a0 = *(const float4*)(fr + l*8);
  float4 a1 = *(const float4*)(fr + l*8 + 4);
  float4 a2 = *(const float4*)(qr + l*4);
  float xv[12] = {a0.x,a0.y,a0.z,a0.w, a1.x,a1.y,a1.z,a1.w, a2.x,a2.y,a2.z,a2.w};
  float s = 0.f, ss = 0.f;
  #pragma unroll
  for (int i = 0; i < 12; i++){ s += xv[i]; ss += xv[i]*xv[i]; }
  #pragma unroll
  for (int off = 1; off < 64; off <<= 1){
    s  += __shfl_xor(s,  off, 64);
    ss += __shfl_xor(ss, off, 64);
  }
  const float inv768 = 1.0f/768.0f;
  float mu = s * inv768;
  float var = ss * inv768 - mu*mu;
  float rstd = 1.0f / sqrtf(var + 1e-6f);
  float4 g0 = *(const float4*)(gamma + l*8);
  float4 g1 = *(const float4*)(gamma + l*8 + 4);
  float4 g2 = *(const float4*)(gamma + 512 + l*4);
  float4 b0 = *(const float4*)(beta + l*8);
  float4 b1 = *(const float4*)(beta + l*8 + 4);
  float4 b2 = *(const float4*)(beta + 512 + l*4);
  float gv[12] = {g0.x,g0.y,g0.z,g0.w, g1.x,g1.y,g1.z,g1.w, g2.x,g2.y,g2.z,g2.w};
  float bv[12] = {b0.x,b0.y,b0.z,b0.w, b1.x,b1.y,b1.z,b1.w, b2.x,b2.y,b2.z,b2.w};
  float ov[12];
  #pragma unroll
  for (int i = 0; i < 12; i++) ov[i] = (xv[i] - mu)*rstd*gv[i] + bv[i];
  float* orow = out + (long long)m * (DM_ + DQ_);
  *(float4*)(orow + l*8)       = make_float4(ov[0], ov[1], ov[2],  ov[3]);
  *(float4*)(orow + l*8 + 4)   = make_float4(ov[4], ov[5], ov[6],  ov[7]);
  *(float4*)(orow + 512 + l*4) = make_float4(ov[8], ov[9], ov[10], ov[11]);
}

extern "C" void kernel_launch(void* const* d_in, const int* in_sizes, int n_in,
                              void* d_out, int out_size, void* d_ws, size_t ws_size,
                              hipStream_t stream){
  const float* q     = (const float*)d_in[0];
  const float* k     = (const float*)d_in[1];
  const float* v     = (const float*)d_in[2];
  const int*   mask  = (const int*)  d_in[3];
  const float* Wq    = (const float*)d_in[4];
  const float* Wk    = (const float*)d_in[5];
  const float* Wv    = (const float*)d_in[6];
  const float* Wfc   = (const float*)d_in[7];
  const float* gamma = (const float*)d_in[8];
  const float* beta  = (const float*)d_in[9];

  char* ws = (char*)d_ws;
  size_t off = 0;
  auto alloc = [&](size_t bytes)->void*{
    void* p = ws + off; off += (bytes + 255) & ~(size_t)255; return p;
  };
  unsigned long long* bits = (unsigned long long*)alloc((size_t)B_*L_*NKW*4);
  short* wqf    = (short*)alloc((size_t)DM_*DQ_*2);
  short* wkf    = (short*)alloc((size_t)DM_*DM_*2);
  short* wvf    = (short*)alloc((size_t)DM_*DM_*2);
  short* wfcf   = (short*)alloc((size_t)DM_*DM_*2);
  short* qh     = (short*)alloc((size_t)B_*H_*L_*DK_*2);
  short* kfr    = (short*)alloc((size_t)B_*H_*L_*DK_*2);
  short* vf     = (short*)alloc((size_t)B_*H_*L_*DK_*2);
  short* attf   = (short*)alloc((size_t)B_*L_*DM_*2);
  float* fc     = (float*)alloc((size_t)B_*L_*DM_*4);

  float* outp  = (float*)d_out;
  float* attnp = outp + (size_t)B_*L_*(DM_ + DQ_);

  { dim3 g(128, 4); k_wprep<<<g, 256, 0, stream>>>(Wq, Wk, Wv, Wfc, wqf, wkf, wvf, wfcf); }
  { dim3 g(128, 4); k_projmask<<<g, 256, 0, stream>>>(q, k, v, wqf, wkf, wvf, qh, kfr, vf, mask, bits); }
  k_attn<<<1024, 256, 0, stream>>>(qh, kfr, vf, (const unsigned*)bits, attf, attnp);
  { dim3 g(64, 8);  k_fc<<<g, 256, 0, stream>>>(attf, wfcf, fc); }
  k_ln<<<1024, 256, 0, stream>>>(fc, q, gamma, beta, outp);
}